// Round 7
// baseline (286.129 us; speedup 1.0000x reference)
//
#include <hip/hip_runtime.h>
#include <math.h>

#define TOK    4096
#define DIM    1024
#define NHEAD  1002
#define NSHORT 1000
#define C0     9000
#define K0     256
#define C1     40257
#define K1     64
#define SP0    64
#define SP1    64
#define PS     64

typedef __attribute__((ext_vector_type(8))) short short8;
typedef __attribute__((ext_vector_type(8))) unsigned short ushort8;
typedef __attribute__((ext_vector_type(4))) float float4v;

__device__ __forceinline__ void gld_lds16(const void* g, void* l) {
    __builtin_amdgcn_global_load_lds(
        (const __attribute__((address_space(1))) unsigned int*)g,
        (__attribute__((address_space(3))) unsigned int*)l,
        16, 0, 0);
}

__device__ __forceinline__ unsigned short f2bf(float f) {
    unsigned int u = __float_as_uint(f);
    return (unsigned short)((u + 0x7FFFu + ((u >> 16) & 1u)) >> 16);
}

__device__ __forceinline__ float bf2f(unsigned short h) {
    return __uint_as_float(((unsigned int)h) << 16);
}

// ---------------- classify targets into cluster lists ----------------
__global__ __launch_bounds__(256) void classify_kernel(
    const int* __restrict__ target, int* __restrict__ cnt,
    int* __restrict__ l0, int* __restrict__ l1)
{
    int t = blockIdx.x * 256 + threadIdx.x;
    if (t >= TOK) return;
    int tg = target[t];
    if (tg >= NSHORT && tg < NSHORT + C0) {
        int i = atomicAdd(&cnt[0], 1); l0[i] = t;
    } else if (tg >= NSHORT + C0) {
        int i = atomicAdd(&cnt[1], 1); l1[i] = t;
    }
}

// ------- weight fp32->bf16 casts in ONE launch (+ zero init). x NOT cast --
#define T0E (NHEAD * DIM / 4)
#define T1E (T0E + K0 * DIM / 4)
#define T2E (T1E + C0 * K0 / 4)
#define T3E (T2E + K1 * DIM / 4)
#define T4E (T3E + C1 * K1 / 4)
__global__ __launch_bounds__(256) void megacast_kernel(
    const float* __restrict__ W_head, const float* __restrict__ W0a,
    const float* __restrict__ W0b, const float* __restrict__ W1a,
    const float* __restrict__ W1b,
    unsigned short* __restrict__ Wheadh, unsigned short* __restrict__ W0ah,
    unsigned short* __restrict__ W0bh, unsigned short* __restrict__ W1ah,
    unsigned short* __restrict__ W1bh,
    int* __restrict__ cnt, float* __restrict__ Shead, float* __restrict__ loss)
{
    int i = blockIdx.x * 256 + threadIdx.x;
    if (i == 0) { cnt[0] = 0; cnt[1] = 0; loss[0] = 0.f; }
    if (i < TOK / 4) ((float4*)Shead)[i] = (float4){0.f, 0.f, 0.f, 0.f};
    const float* src; unsigned short* dst; int off;
    if      (i < T0E) { src = W_head; dst = Wheadh; off = i; }
    else if (i < T1E) { src = W0a;    dst = W0ah;   off = i - T0E; }
    else if (i < T2E) { src = W0b;    dst = W0bh;   off = i - T1E; }
    else if (i < T3E) { src = W1a;    dst = W1ah;   off = i - T2E; }
    else if (i < T4E) { src = W1b;    dst = W1bh;   off = i - T3E; }
    else return;
    float4 v = ((const float4*)src)[off];
    ushort4 o;
    o.x = f2bf(v.x); o.y = f2bf(v.y); o.z = f2bf(v.z); o.w = f2bf(v.w);
    ((ushort4*)dst)[off] = o;
}

// ---- 128x64x64 MFMA GEMM, A = fp32 x cast in staging, head-softmax-fused -
// 1-D grid 672, XCD swizzle: xcd=id&7, j=id>>3, bx=j%21, by=xcd+8*(j/21).
// bx: [0,16) head col-tiles (exp-sum epilogue), [16,20) XA0, [20] XA1.
// 4 waves 2x2; wave tile 64x32. LDS 48 KB dbuf -> 3 blocks/CU.
__global__ __launch_bounds__(256, 3) void gemm_x32(
    const float* __restrict__ X,
    const unsigned short* __restrict__ Wheadh, const unsigned short* __restrict__ W0ah,
    const unsigned short* __restrict__ W1ah,
    const int* __restrict__ target,
    float* __restrict__ Shead, float* __restrict__ g0, float* __restrict__ g1,
    float* __restrict__ th,
    unsigned short* __restrict__ XA0h, unsigned short* __restrict__ XA1h)
{
    const int id = blockIdx.x;
    const int xcd = id & 7, j = id >> 3;
    const int bx = j % 21, by = xcd + 8 * (j / 21);

    const unsigned short* Bh; int nrows, bn, seg, ldY; unsigned short* Yh;
    if (bx < 16)      { seg = 0; Bh = Wheadh; nrows = NHEAD; bn = bx * 64;        Yh = nullptr; ldY = 0; }
    else if (bx < 20) { seg = 1; Bh = W0ah;   nrows = K0;    bn = (bx - 16) * 64; Yh = XA0h;    ldY = K0; }
    else              { seg = 2; Bh = W1ah;   nrows = K1;    bn = 0;              Yh = XA1h;    ldY = K1; }
    const int bm = by * 128;

    __shared__ short ldsA[2][8192];   // 16 chunks x 512 shorts (128 rows x 64 k)
    __shared__ short ldsB[2][4096];   // 8 chunks  (64 rows x 64 k)
    const int tid = threadIdx.x, wv = tid >> 6, lane = tid & 63;
    const int nn = lane & 15, q = lane >> 4;
    const int wr = wv >> 1, wc = wv & 1;

    float4v acc[4][2];
    #pragma unroll
    for (int i = 0; i < 4; ++i)
        #pragma unroll
        for (int jj = 0; jj < 2; ++jj) acc[i][jj] = (float4v){0.f, 0.f, 0.f, 0.f};

    auto stage = [&](int b, int kk) {
        #pragma unroll
        for (int i2 = 0; i2 < 6; ++i2) {
            int ch = wv * 6 + i2;
            if (ch < 16) {
                // A: fp32 global -> bf16 cvt -> ds_write_b128 (fragment order)
                int rg = ch >> 1, kc = ch & 1;
                int row = bm + rg * 16 + nn;
                const float* gp = X + (size_t)row * DIM + kk + kc * 32 + q * 8;
                float4 v0 = *(const float4*)gp;
                float4 v1 = *(const float4*)(gp + 4);
                ushort8 pk;
                pk[0] = f2bf(v0.x); pk[1] = f2bf(v0.y); pk[2] = f2bf(v0.z); pk[3] = f2bf(v0.w);
                pk[4] = f2bf(v1.x); pk[5] = f2bf(v1.y); pk[6] = f2bf(v1.z); pk[7] = f2bf(v1.w);
                *(ushort8*)&ldsA[b][ch * 512 + lane * 8] = pk;
            } else {
                int bc = ch - 16, rg = bc >> 1, kc = bc & 1;
                int row = bn + rg * 16 + nn;
                if (row > nrows - 1) row = nrows - 1;
                gld_lds16(Bh + (size_t)row * DIM + kk + kc * 32 + q * 8, &ldsB[b][bc * 512]);
            }
        }
    };

    int buf = 0;
    stage(0, 0);
    __syncthreads();
    for (int s = 0; s < DIM / 64; ++s) {
        if (s + 1 < DIM / 64) stage(buf ^ 1, (s + 1) * 64);
        short8 afr[4][2], bfr[2][2];
        #pragma unroll
        for (int i = 0; i < 4; ++i)
            #pragma unroll
            for (int kc = 0; kc < 2; ++kc)
                afr[i][kc] = *(const short8*)&ldsA[buf][((wr * 4 + i) * 2 + kc) * 512 + lane * 8];
        #pragma unroll
        for (int jj = 0; jj < 2; ++jj)
            #pragma unroll
            for (int kc = 0; kc < 2; ++kc)
                bfr[jj][kc] = *(const short8*)&ldsB[buf][((wc * 2 + jj) * 2 + kc) * 512 + lane * 8];
        #pragma unroll
        for (int kc = 0; kc < 2; ++kc)
            #pragma unroll
            for (int i = 0; i < 4; ++i)
                #pragma unroll
                for (int jj = 0; jj < 2; ++jj)
                    acc[i][jj] = __builtin_amdgcn_mfma_f32_16x16x32_bf16(afr[i][kc], bfr[jj][kc], acc[i][jj], 0, 0, 0);
        __syncthreads();
        buf ^= 1;
    }

    if (seg == 0) {
        #pragma unroll
        for (int i = 0; i < 4; ++i) {
            int rowr[4], tg[4];
            float s[4] = {0.f, 0.f, 0.f, 0.f};
            #pragma unroll
            for (int r = 0; r < 4; ++r) {
                rowr[r] = bm + wr * 64 + i * 16 + q * 4 + r;
                tg[r] = target[rowr[r]];
            }
            #pragma unroll
            for (int jj = 0; jj < 2; ++jj) {
                int col = bn + wc * 32 + jj * 16 + nn;
                bool cv = (col < NHEAD);
                #pragma unroll
                for (int r = 0; r < 4; ++r) {
                    float v = acc[i][jj][r];
                    if (cv) {
                        s[r] += __expf(v);
                        if (col == 1000) g0[rowr[r]] = v;
                        if (col == 1001) g1[rowr[r]] = v;
                        if (tg[r] < NSHORT && col == tg[r]) th[rowr[r]] = v;
                    }
                }
            }
            #pragma unroll
            for (int off = 1; off < 16; off <<= 1)
                #pragma unroll
                for (int r = 0; r < 4; ++r) s[r] += __shfl_xor(s[r], off, 64);
            if (nn == 0) {
                #pragma unroll
                for (int r = 0; r < 4; ++r) atomicAdd(&Shead[rowr[r]], s[r]);
            }
        }
    } else {
        #pragma unroll
        for (int i = 0; i < 4; ++i)
            #pragma unroll
            for (int jj = 0; jj < 2; ++jj) {
                int col = bn + wc * 32 + jj * 16 + nn;
                if (col < nrows) {
                    #pragma unroll
                    for (int r = 0; r < 4; ++r) {
                        int row = bm + wr * 64 + i * 16 + q * 4 + r;
                        Yh[(size_t)row * ldY + col] = f2bf(acc[i][jj][r]);
                    }
                }
            }
    }
}

// ------- cluster exp-sum: LDS-staged MFMA + exp; MT m-tiles per wave ------
// Block covers MT*64 tokens (4 waves x MT tiles of 16). G ctiles per buffer.
template<int K, int G, int MT>
__global__ __launch_bounds__(256) void cluster_lse2(
    const unsigned short* __restrict__ XAh, const unsigned short* __restrict__ Wbh,
    int C, const int* __restrict__ list, const int* __restrict__ cnt, int ci,
    int tps, float* __restrict__ psum)
{
    constexpr int NCH = K / 32;
    constexpr int CPB = G * NCH;
    constexpr int TT = MT * 64;
    const int n = cnt[ci];
    if ((int)blockIdx.x * TT >= n) return;
    __shared__ short lds[2][CPB * 512];
    const int tid = threadIdx.x, wv = tid >> 6, lane = tid & 63;
    const int m = lane & 15, q = lane >> 4;
    const int nT = (C + 15) / 16;
    const int T0 = blockIdx.y * tps;
    const int T1 = min(T0 + tps, nT);
    if (T0 >= nT) return;

    short8 a[MT][NCH];
    #pragma unroll
    for (int t = 0; t < MT; ++t) {
        int iTok = blockIdx.x * TT + t * 64 + wv * 16 + m;
        int tok = list[(iTok < n) ? iTok : (n - 1)];
        const unsigned short* ap = XAh + (size_t)tok * K + q * 8;
        #pragma unroll
        for (int kc = 0; kc < NCH; ++kc) a[t][kc] = *(const short8*)(ap + kc * 32);
    }

    float s[MT][4] = {};

    auto stage = [&](int b, int Tb) {
        #pragma unroll
        for (int i = 0; i < CPB / 4; ++i) {
            int ch = wv * (CPB / 4) + i;
            int g = ch / NCH, kc = ch % NCH;
            int row = (Tb + g) * 16 + m;
            if (row > C - 1) row = C - 1;
            gld_lds16(Wbh + (size_t)row * K + kc * 32 + q * 8, &lds[b][ch * 512]);
        }
    };

    int buf = 0;
    stage(0, T0);
    __syncthreads();
    for (int Tb = T0; Tb < T1; Tb += G) {
        if (Tb + G < T1) stage(buf ^ 1, Tb + G);
        #pragma unroll
        for (int g = 0; g < G; ++g) {
            if (Tb + g < T1) {
                float4v av[MT];
                #pragma unroll
                for (int t = 0; t < MT; ++t) av[t] = (float4v){0.f, 0.f, 0.f, 0.f};
                #pragma unroll
                for (int kc = 0; kc < NCH; ++kc) {
                    short8 bfr = *(const short8*)&lds[buf][(g * NCH + kc) * 512 + lane * 8];
                    #pragma unroll
                    for (int t = 0; t < MT; ++t)
                        av[t] = __builtin_amdgcn_mfma_f32_16x16x32_bf16(a[t][kc], bfr, av[t], 0, 0, 0);
                }
                int jcl = (Tb + g) * 16 + m;
                if (jcl < C) {
                    #pragma unroll
                    for (int t = 0; t < MT; ++t)
                        #pragma unroll
                        for (int r = 0; r < 4; ++r) s[t][r] += __expf(av[t][r]);
                }
            }
        }
        __syncthreads();
        buf ^= 1;
    }
    #pragma unroll
    for (int off = 1; off < 16; off <<= 1) {
        #pragma unroll
        for (int t = 0; t < MT; ++t)
            #pragma unroll
            for (int r = 0; r < 4; ++r)
                s[t][r] += __shfl_xor(s[t][r], off, 64);
    }
    if (m == 0) {
        #pragma unroll
        for (int t = 0; t < MT; ++t)
            #pragma unroll
            for (int r = 0; r < 4; ++r) {
                int r0 = blockIdx.x * TT + t * 64 + wv * 16 + q * 4 + r;
                if (r0 < n) psum[(size_t)r0 * PS + blockIdx.y] = s[t][r];
            }
    }
}

// ------- finish: shortlist out + cluster target dot/psum/gate + loss ------
__global__ __launch_bounds__(256) void finish_kernel(
    const unsigned short* __restrict__ XA0h, const unsigned short* __restrict__ W0bh,
    const unsigned short* __restrict__ XA1h, const unsigned short* __restrict__ W1bh,
    const int* __restrict__ l0, const int* __restrict__ l1,
    const int* __restrict__ cnt, const int* __restrict__ target,
    const float* __restrict__ psum0, const float* __restrict__ psum1,
    const float* __restrict__ Shead, const float* __restrict__ g0,
    const float* __restrict__ g1, const float* __restrict__ th,
    int tps0, int tps1, float* __restrict__ out, float* __restrict__ loss)
{
    const int y = blockIdx.y;
    const int tid = threadIdx.x, wv = tid >> 6, lane = tid & 63;
    float contrib = 0.f;
    if (y == 2) {
        int t = blockIdx.x * 256 + tid;
        if (t < TOK) {
            int tg = target[t];
            if (tg < NSHORT) {
                float v = th[t] - logf(Shead[t]);
                out[t] = v;
                contrib = v;
            }
        }
    } else {
        const int ci = y;
        const int n = cnt[ci];
        int i = blockIdx.x * 4 + wv;
        if (i < n) {
            const int* list = ci ? l1 : l0;
            int tok = list[i];
            float dot = 0.f, S;
            if (ci == 0) {
                int tg = target[tok] - NSHORT;
                const unsigned short* xp = XA0h + (size_t)tok * K0;
                const unsigned short* wp = W0bh + (size_t)tg * K0;
                #pragma unroll
                for (int k = 0; k < K0 / 64; ++k)
                    dot += bf2f(xp[lane + k * 64]) * bf2f(wp[lane + k * 64]);
                int nT = (C0 + 15) / 16;
                S = (lane * tps0 < nT) ? psum0[(size_t)i * PS + lane] : 0.f;
            } else {
                int tg = target[tok] - (NSHORT + C0);
                dot = bf2f(XA1h[(size_t)tok * K1 + lane]) * bf2f(W1bh[(size_t)tg * K1 + lane]);
                int nT = (C1 + 15) / 16;
                S = (lane * tps1 < nT) ? psum1[(size_t)i * PS + lane] : 0.f;
            }
            #pragma unroll
            for (int off = 32; off; off >>= 1) {
                dot += __shfl_xor(dot, off, 64);
                S   += __shfl_xor(S, off, 64);
            }
            if (lane == 0) {
                float gate = (ci ? g1[tok] : g0[tok]) - logf(Shead[tok]);
                float v = dot - logf(S) + gate;
                out[tok] = v;
                contrib = v;
            }
        }
    }
    __shared__ float red[4];
    #pragma unroll
    for (int off = 32; off; off >>= 1) contrib += __shfl_xor(contrib, off, 64);
    if (lane == 0) red[wv] = contrib;
    __syncthreads();
    if (tid == 0) {
        float t = red[0] + red[1] + red[2] + red[3];
        if (t != 0.f) atomicAdd(loss, -t / (float)TOK);
    }
}

extern "C" void kernel_launch(void* const* d_in, const int* in_sizes, int n_in,
                              void* d_out, int out_size, void* d_ws, size_t ws_size,
                              hipStream_t stream) {
    const float* x      = (const float*)d_in[0];
    const int*   target = (const int*)  d_in[1];
    const float* W_head = (const float*)d_in[2];
    const float* W0a    = (const float*)d_in[3];
    const float* W0b    = (const float*)d_in[4];
    const float* W1a    = (const float*)d_in[5];
    const float* W1b    = (const float*)d_in[6];
    float* out  = (float*)d_out;
    float* loss = out + TOK;

    float* ws     = (float*)d_ws;
    float* Shead  = ws;                               // 4096
    float* g0     = Shead + TOK;                      // 4096
    float* g1     = g0 + TOK;                         // 4096
    float* th     = g1 + TOK;                         // 4096
    float* psum0  = th + TOK;                         // 4096*64
    float* psum1  = psum0 + (size_t)TOK * PS;         // 4096*64
    unsigned short* Wheadh = (unsigned short*)(psum1 + (size_t)TOK * PS);
    unsigned short* W0ah   = Wheadh + (size_t)NHEAD * DIM;
    unsigned short* W0bh   = W0ah + (size_t)K0 * DIM;
    unsigned short* W1ah   = W0bh + (size_t)C0 * K0;
    unsigned short* W1bh   = W1ah + (size_t)K1 * DIM;
    unsigned short* XA0h   = W1bh + (size_t)C1 * K1;
    unsigned short* XA1h   = XA0h + (size_t)TOK * K0;
    int* cnt = (int*)(XA1h + (size_t)TOK * K1);
    int* l0  = cnt + 8;
    int* l1  = l0 + TOK;

    megacast_kernel<<<(T4E + 255) / 256, 256, 0, stream>>>(
        W_head, W0a, W0b, W1a, W1b, Wheadh, W0ah, W0bh, W1ah, W1bh,
        cnt, Shead, loss);
    classify_kernel<<<TOK / 256, 256, 0, stream>>>(target, cnt, l0, l1);

    gemm_x32<<<672, 256, 0, stream>>>(
        x, Wheadh, W0ah, W1ah, target, Shead, g0, g1, th, XA0h, XA1h);

    int nT0 = (C0 + 15) / 16;                  // 563
    int tps0 = (nT0 + SP0 - 1) / SP0;          // 9
    cluster_lse2<K0, 2, 2><<<dim3(TOK / 128, SP0), 256, 0, stream>>>(
        XA0h, W0bh, C0, l0, cnt, 0, tps0, psum0);
    int nT1 = (C1 + 15) / 16;                  // 2517
    int tps1 = (nT1 + SP1 - 1) / SP1;          // 40
    cluster_lse2<K1, 4, 4><<<dim3(TOK / 256, SP1), 256, 0, stream>>>(
        XA1h, W1bh, C1, l1, cnt, 1, tps1, psum1);

    finish_kernel<<<dim3(1024, 3), 256, 0, stream>>>(
        XA0h, W0bh, XA1h, W1bh, l0, l1, cnt, target, psum0, psum1,
        Shead, g0, g1, th, tps0, tps1, out, loss);
}

// Round 8
// 243.232 us; speedup vs baseline: 1.1764x; 1.1764x over previous
//
#include <hip/hip_runtime.h>
#include <math.h>

#define TOK    4096
#define DIM    1024
#define NHEAD  1002
#define NSHORT 1000
#define C0     9000
#define K0     256
#define C1     40257
#define K1     64
#define SP0    64
#define SP1    64
#define PS     64

typedef __attribute__((ext_vector_type(8))) short short8;
typedef __attribute__((ext_vector_type(4))) float float4v;

__device__ __forceinline__ void gld_lds16(const void* g, void* l) {
    __builtin_amdgcn_global_load_lds(
        (const __attribute__((address_space(1))) unsigned int*)g,
        (__attribute__((address_space(3))) unsigned int*)l,
        16, 0, 0);
}

__device__ __forceinline__ unsigned short f2bf(float f) {
    unsigned int u = __float_as_uint(f);
    return (unsigned short)((u + 0x7FFFu + ((u >> 16) & 1u)) >> 16);
}

__device__ __forceinline__ float bf2f(unsigned short h) {
    return __uint_as_float(((unsigned int)h) << 16);
}

// -------- all fp32->bf16 casts (x + weights) in ONE launch + init ---------
#define S0E (TOK * DIM / 4)
#define S1E (S0E + NHEAD * DIM / 4)
#define S2E (S1E + K0 * DIM / 4)
#define S3E (S2E + C0 * K0 / 4)
#define S4E (S3E + K1 * DIM / 4)
#define S5E (S4E + C1 * K1 / 4)
__global__ __launch_bounds__(256) void megacast_kernel(
    const float* __restrict__ x, const float* __restrict__ W_head,
    const float* __restrict__ W0a, const float* __restrict__ W0b,
    const float* __restrict__ W1a, const float* __restrict__ W1b,
    unsigned short* __restrict__ xh, unsigned short* __restrict__ Wheadh,
    unsigned short* __restrict__ W0ah, unsigned short* __restrict__ W0bh,
    unsigned short* __restrict__ W1ah, unsigned short* __restrict__ W1bh,
    int* __restrict__ cnt, float* __restrict__ Shead, float* __restrict__ loss)
{
    int i = blockIdx.x * 256 + threadIdx.x;
    if (i == 0) { cnt[0] = 0; cnt[1] = 0; loss[0] = 0.f; }
    if (i < TOK / 4) ((float4*)Shead)[i] = (float4){0.f, 0.f, 0.f, 0.f};
    const float* src; unsigned short* dst; int off;
    if      (i < S0E) { src = x;      dst = xh;     off = i; }
    else if (i < S1E) { src = W_head; dst = Wheadh; off = i - S0E; }
    else if (i < S2E) { src = W0a;    dst = W0ah;   off = i - S1E; }
    else if (i < S3E) { src = W0b;    dst = W0bh;   off = i - S2E; }
    else if (i < S4E) { src = W1a;    dst = W1ah;   off = i - S3E; }
    else if (i < S5E) { src = W1b;    dst = W1bh;   off = i - S4E; }
    else return;
    float4 v = ((const float4*)src)[off];
    ushort4 o;
    o.x = f2bf(v.x); o.y = f2bf(v.y); o.z = f2bf(v.z); o.w = f2bf(v.w);
    ((ushort4*)dst)[off] = o;
}

// ---- 128x64x64 bf16 MFMA GEMM (async gld_lds staging), XCD-swizzled, ----
// ---- head-softmax-fused; blocks [672,688) do target classification. -----
// id<672: xcd=id&7, j=id>>3, bx=j%21, by=xcd+8*(j/21).
// bx: [0,16) head col-tiles (exp-sum epilogue, H never stored),
//     [16,20) XA0, [20] XA1 (bf16 store). 4 waves 2x2; wave tile 64x32.
__global__ __launch_bounds__(256, 3) void gemm_sw(
    const unsigned short* __restrict__ Ah,
    const unsigned short* __restrict__ Wheadh, const unsigned short* __restrict__ W0ah,
    const unsigned short* __restrict__ W1ah,
    const int* __restrict__ target,
    float* __restrict__ Shead, float* __restrict__ g0, float* __restrict__ g1,
    float* __restrict__ th,
    unsigned short* __restrict__ XA0h, unsigned short* __restrict__ XA1h,
    int* __restrict__ cnt, int* __restrict__ l0, int* __restrict__ l1)
{
    const int id = blockIdx.x;
    if (id >= 672) {
        // classification blocks
        int t = (id - 672) * 256 + threadIdx.x;
        if (t < TOK) {
            int tg = target[t];
            if (tg >= NSHORT && tg < NSHORT + C0) {
                int i = atomicAdd(&cnt[0], 1); l0[i] = t;
            } else if (tg >= NSHORT + C0) {
                int i = atomicAdd(&cnt[1], 1); l1[i] = t;
            }
        }
        return;
    }
    const int xcd = id & 7, j = id >> 3;
    const int bx = j % 21, by = xcd + 8 * (j / 21);

    const unsigned short* Bh; int nrows, bn, seg, ldY; unsigned short* Yh;
    if (bx < 16)      { seg = 0; Bh = Wheadh; nrows = NHEAD; bn = bx * 64;        Yh = nullptr; ldY = 0; }
    else if (bx < 20) { seg = 1; Bh = W0ah;   nrows = K0;    bn = (bx - 16) * 64; Yh = XA0h;    ldY = K0; }
    else              { seg = 2; Bh = W1ah;   nrows = K1;    bn = 0;              Yh = XA1h;    ldY = K1; }
    const int bm = by * 128;

    __shared__ short ldsA[2][8192];   // 16 chunks x 512 shorts (128 rows x 64 k)
    __shared__ short ldsB[2][4096];   // 8 chunks  (64 rows x 64 k)
    const int tid = threadIdx.x, wv = tid >> 6, lane = tid & 63;
    const int nn = lane & 15, q = lane >> 4;
    const int wr = wv >> 1, wc = wv & 1;

    float4v acc[4][2];
    #pragma unroll
    for (int i = 0; i < 4; ++i)
        #pragma unroll
        for (int jj = 0; jj < 2; ++jj) acc[i][jj] = (float4v){0.f, 0.f, 0.f, 0.f};

    auto stage = [&](int b, int kk) {
        #pragma unroll
        for (int i2 = 0; i2 < 6; ++i2) {
            int ch = wv * 6 + i2;
            if (ch < 16) {
                int rg = ch >> 1, kc = ch & 1;
                int row = bm + rg * 16 + nn;
                gld_lds16(Ah + (size_t)row * DIM + kk + kc * 32 + q * 8, &ldsA[b][ch * 512]);
            } else {
                int bc = ch - 16, rg = bc >> 1, kc = bc & 1;
                int row = bn + rg * 16 + nn;
                if (row > nrows - 1) row = nrows - 1;
                gld_lds16(Bh + (size_t)row * DIM + kk + kc * 32 + q * 8, &ldsB[b][bc * 512]);
            }
        }
    };

    int buf = 0;
    stage(0, 0);
    __syncthreads();
    for (int s = 0; s < DIM / 64; ++s) {
        if (s + 1 < DIM / 64) stage(buf ^ 1, (s + 1) * 64);
        short8 afr[4][2], bfr[2][2];
        #pragma unroll
        for (int i = 0; i < 4; ++i)
            #pragma unroll
            for (int kc = 0; kc < 2; ++kc)
                afr[i][kc] = *(const short8*)&ldsA[buf][((wr * 4 + i) * 2 + kc) * 512 + lane * 8];
        #pragma unroll
        for (int jj = 0; jj < 2; ++jj)
            #pragma unroll
            for (int kc = 0; kc < 2; ++kc)
                bfr[jj][kc] = *(const short8*)&ldsB[buf][((wc * 2 + jj) * 2 + kc) * 512 + lane * 8];
        #pragma unroll
        for (int kc = 0; kc < 2; ++kc)
            #pragma unroll
            for (int i = 0; i < 4; ++i)
                #pragma unroll
                for (int jj = 0; jj < 2; ++jj)
                    acc[i][jj] = __builtin_amdgcn_mfma_f32_16x16x32_bf16(afr[i][kc], bfr[jj][kc], acc[i][jj], 0, 0, 0);
        __syncthreads();
        buf ^= 1;
    }

    if (seg == 0) {
        #pragma unroll
        for (int i = 0; i < 4; ++i) {
            int rowr[4], tg[4];
            float s[4] = {0.f, 0.f, 0.f, 0.f};
            #pragma unroll
            for (int r = 0; r < 4; ++r) {
                rowr[r] = bm + wr * 64 + i * 16 + q * 4 + r;
                tg[r] = target[rowr[r]];
            }
            #pragma unroll
            for (int jj = 0; jj < 2; ++jj) {
                int col = bn + wc * 32 + jj * 16 + nn;
                bool cv = (col < NHEAD);
                #pragma unroll
                for (int r = 0; r < 4; ++r) {
                    float v = acc[i][jj][r];
                    if (cv) {
                        s[r] += __expf(v);
                        if (col == 1000) g0[rowr[r]] = v;
                        if (col == 1001) g1[rowr[r]] = v;
                        if (tg[r] < NSHORT && col == tg[r]) th[rowr[r]] = v;
                    }
                }
            }
            #pragma unroll
            for (int off = 1; off < 16; off <<= 1)
                #pragma unroll
                for (int r = 0; r < 4; ++r) s[r] += __shfl_xor(s[r], off, 64);
            if (nn == 0) {
                #pragma unroll
                for (int r = 0; r < 4; ++r) atomicAdd(&Shead[rowr[r]], s[r]);
            }
        }
    } else {
        #pragma unroll
        for (int i = 0; i < 4; ++i)
            #pragma unroll
            for (int jj = 0; jj < 2; ++jj) {
                int col = bn + wc * 32 + jj * 16 + nn;
                if (col < nrows) {
                    #pragma unroll
                    for (int r = 0; r < 4; ++r) {
                        int row = bm + wr * 64 + i * 16 + q * 4 + r;
                        Yh[(size_t)row * ldY + col] = f2bf(acc[i][jj][r]);
                    }
                }
            }
    }
}

// ------- cluster exp-sum body: LDS-staged MFMA + exp; MT m-tiles/wave -----
template<int K, int G, int MT>
__device__ __forceinline__ void cluster_body(
    const unsigned short* __restrict__ XAh, const unsigned short* __restrict__ Wbh,
    int C, const int* __restrict__ list, int n, int sp, int tps,
    float* __restrict__ psum, short (*lds)[8192])
{
    constexpr int NCH = K / 32;
    constexpr int CPB = G * NCH;
    constexpr int TT = MT * 64;
    if ((int)blockIdx.x * TT >= n) return;
    const int tid = threadIdx.x, wv = tid >> 6, lane = tid & 63;
    const int m = lane & 15, q = lane >> 4;
    const int nT = (C + 15) / 16;
    const int T0 = sp * tps;
    const int T1 = min(T0 + tps, nT);
    if (T0 >= nT) return;

    short8 a[MT][NCH];
    #pragma unroll
    for (int t = 0; t < MT; ++t) {
        int iTok = blockIdx.x * TT + t * 64 + wv * 16 + m;
        int tok = list[(iTok < n) ? iTok : (n - 1)];
        const unsigned short* ap = XAh + (size_t)tok * K + q * 8;
        #pragma unroll
        for (int kc = 0; kc < NCH; ++kc) a[t][kc] = *(const short8*)(ap + kc * 32);
    }

    float s[MT][4] = {};

    auto stage = [&](int b, int Tb) {
        #pragma unroll
        for (int i = 0; i < CPB / 4; ++i) {
            int ch = wv * (CPB / 4) + i;
            int g = ch / NCH, kc = ch % NCH;
            int row = (Tb + g) * 16 + m;
            if (row > C - 1) row = C - 1;
            gld_lds16(Wbh + (size_t)row * K + kc * 32 + q * 8, &lds[b][ch * 512]);
        }
    };

    int buf = 0;
    stage(0, T0);
    __syncthreads();
    for (int Tb = T0; Tb < T1; Tb += G) {
        if (Tb + G < T1) stage(buf ^ 1, Tb + G);
        #pragma unroll
        for (int g = 0; g < G; ++g) {
            if (Tb + g < T1) {
                float4v av[MT];
                #pragma unroll
                for (int t = 0; t < MT; ++t) av[t] = (float4v){0.f, 0.f, 0.f, 0.f};
                #pragma unroll
                for (int kc = 0; kc < NCH; ++kc) {
                    short8 bfr = *(const short8*)&lds[buf][(g * NCH + kc) * 512 + lane * 8];
                    #pragma unroll
                    for (int t = 0; t < MT; ++t)
                        av[t] = __builtin_amdgcn_mfma_f32_16x16x32_bf16(a[t][kc], bfr, av[t], 0, 0, 0);
                }
                int jcl = (Tb + g) * 16 + m;
                if (jcl < C) {
                    #pragma unroll
                    for (int t = 0; t < MT; ++t)
                        #pragma unroll
                        for (int r = 0; r < 4; ++r) s[t][r] += __expf(av[t][r]);
                }
            }
        }
        __syncthreads();
        buf ^= 1;
    }
    #pragma unroll
    for (int off = 1; off < 16; off <<= 1) {
        #pragma unroll
        for (int t = 0; t < MT; ++t)
            #pragma unroll
            for (int r = 0; r < 4; ++r)
                s[t][r] += __shfl_xor(s[t][r], off, 64);
    }
    if (m == 0) {
        #pragma unroll
        for (int t = 0; t < MT; ++t)
            #pragma unroll
            for (int r = 0; r < 4; ++r) {
                int r0 = blockIdx.x * TT + t * 64 + wv * 16 + q * 4 + r;
                if (r0 < n) psum[(size_t)r0 * PS + sp] = s[t][r];
            }
    }
}

// ------- merged cluster kernel: y<SP0 -> cluster0, else cluster1 ----------
__global__ __launch_bounds__(256) void cluster_kernel(
    const unsigned short* __restrict__ XA0h, const unsigned short* __restrict__ W0bh,
    const unsigned short* __restrict__ XA1h, const unsigned short* __restrict__ W1bh,
    const int* __restrict__ l0, const int* __restrict__ l1,
    const int* __restrict__ cnt, int tps0, int tps1,
    float* __restrict__ psum0, float* __restrict__ psum1)
{
    __shared__ short lds[2][8192];   // 32 KB shared by both paths
    if (blockIdx.y < SP0) {
        cluster_body<K0, 2, 2>(XA0h, W0bh, C0, l0, cnt[0], blockIdx.y, tps0, psum0, lds);
    } else {
        if (blockIdx.x >= 16) return;
        cluster_body<K1, 4, 4>(XA1h, W1bh, C1, l1, cnt[1], blockIdx.y - SP0, tps1, psum1, lds);
    }
}

// ------- finish: shortlist out + cluster target dot/psum/gate + loss ------
__global__ __launch_bounds__(256) void finish_kernel(
    const unsigned short* __restrict__ XA0h, const unsigned short* __restrict__ W0bh,
    const unsigned short* __restrict__ XA1h, const unsigned short* __restrict__ W1bh,
    const int* __restrict__ l0, const int* __restrict__ l1,
    const int* __restrict__ cnt, const int* __restrict__ target,
    const float* __restrict__ psum0, const float* __restrict__ psum1,
    const float* __restrict__ Shead, const float* __restrict__ g0,
    const float* __restrict__ g1, const float* __restrict__ th,
    int tps0, int tps1, float* __restrict__ out, float* __restrict__ loss)
{
    const int y = blockIdx.y;
    const int tid = threadIdx.x, wv = tid >> 6, lane = tid & 63;
    float contrib = 0.f;
    if (y == 2) {
        int t = blockIdx.x * 256 + tid;
        if (t < TOK) {
            int tg = target[t];
            if (tg < NSHORT) {
                float v = th[t] - logf(Shead[t]);
                out[t] = v;
                contrib = v;
            }
        }
    } else {
        const int ci = y;
        const int n = cnt[ci];
        int i = blockIdx.x * 4 + wv;
        if (i < n) {
            const int* list = ci ? l1 : l0;
            int tok = list[i];
            float dot = 0.f, S;
            if (ci == 0) {
                int tg = target[tok] - NSHORT;
                const unsigned short* xp = XA0h + (size_t)tok * K0;
                const unsigned short* wp = W0bh + (size_t)tg * K0;
                #pragma unroll
                for (int k = 0; k < K0 / 64; ++k)
                    dot += bf2f(xp[lane + k * 64]) * bf2f(wp[lane + k * 64]);
                int nT = (C0 + 15) / 16;
                S = (lane * tps0 < nT) ? psum0[(size_t)i * PS + lane] : 0.f;
            } else {
                int tg = target[tok] - (NSHORT + C0);
                dot = bf2f(XA1h[(size_t)tok * K1 + lane]) * bf2f(W1bh[(size_t)tg * K1 + lane]);
                int nT = (C1 + 15) / 16;
                S = (lane * tps1 < nT) ? psum1[(size_t)i * PS + lane] : 0.f;
            }
            #pragma unroll
            for (int off = 32; off; off >>= 1) {
                dot += __shfl_xor(dot, off, 64);
                S   += __shfl_xor(S, off, 64);
            }
            if (lane == 0) {
                float gate = (ci ? g1[tok] : g0[tok]) - logf(Shead[tok]);
                float v = dot - logf(S) + gate;
                out[tok] = v;
                contrib = v;
            }
        }
    }
    __shared__ float red[4];
    #pragma unroll
    for (int off = 32; off; off >>= 1) contrib += __shfl_xor(contrib, off, 64);
    if (lane == 0) red[wv] = contrib;
    __syncthreads();
    if (tid == 0) {
        float t = red[0] + red[1] + red[2] + red[3];
        if (t != 0.f) atomicAdd(loss, -t / (float)TOK);
    }
}

extern "C" void kernel_launch(void* const* d_in, const int* in_sizes, int n_in,
                              void* d_out, int out_size, void* d_ws, size_t ws_size,
                              hipStream_t stream) {
    const float* x      = (const float*)d_in[0];
    const int*   target = (const int*)  d_in[1];
    const float* W_head = (const float*)d_in[2];
    const float* W0a    = (const float*)d_in[3];
    const float* W0b    = (const float*)d_in[4];
    const float* W1a    = (const float*)d_in[5];
    const float* W1b    = (const float*)d_in[6];
    float* out  = (float*)d_out;
    float* loss = out + TOK;

    float* ws     = (float*)d_ws;
    float* Shead  = ws;                               // 4096
    float* g0     = Shead + TOK;                      // 4096
    float* g1     = g0 + TOK;                         // 4096
    float* th     = g1 + TOK;                         // 4096
    float* psum0  = th + TOK;                         // 4096*64
    float* psum1  = psum0 + (size_t)TOK * PS;         // 4096*64
    unsigned short* xh     = (unsigned short*)(psum1 + (size_t)TOK * PS);
    unsigned short* Wheadh = xh + (size_t)TOK * DIM;
    unsigned short* W0ah   = Wheadh + (size_t)NHEAD * DIM;
    unsigned short* W0bh   = W0ah + (size_t)K0 * DIM;
    unsigned short* W1ah   = W0bh + (size_t)C0 * K0;
    unsigned short* W1bh   = W1ah + (size_t)K1 * DIM;
    unsigned short* XA0h   = W1bh + (size_t)C1 * K1;
    unsigned short* XA1h   = XA0h + (size_t)TOK * K0;
    int* cnt = (int*)(XA1h + (size_t)TOK * K1);
    int* l0  = cnt + 8;
    int* l1  = l0 + TOK;

    int tps0 = ((C0 + 15) / 16 + SP0 - 1) / SP0;   // 9
    int tps1 = ((C1 + 15) / 16 + SP1 - 1) / SP1;   // 40

    megacast_kernel<<<(S5E + 255) / 256, 256, 0, stream>>>(
        x, W_head, W0a, W0b, W1a, W1b, xh, Wheadh, W0ah, W0bh, W1ah, W1bh,
        cnt, Shead, loss);

    gemm_sw<<<688, 256, 0, stream>>>(
        xh, Wheadh, W0ah, W1ah, target, Shead, g0, g1, th, XA0h, XA1h,
        cnt, l0, l1);

    cluster_kernel<<<dim3(TOK / 128, SP0 + SP1), 256, 0, stream>>>(
        XA0h, W0bh, XA1h, W1bh, l0, l1, cnt, tps0, tps1, psum0, psum1);

    finish_kernel<<<dim3(1024, 3), 256, 0, stream>>>(
        XA0h, W0bh, XA1h, W1bh, l0, l1, cnt, target, psum0, psum1,
        Shead, g0, g1, th, tps0, tps1, out, loss);
}

// Round 9
// 236.457 us; speedup vs baseline: 1.2101x; 1.0286x over previous
//
#include <hip/hip_runtime.h>
#include <math.h>

#define TOK    4096
#define DIM    1024
#define NHEAD  1002
#define NSHORT 1000
#define C0     9000
#define K0     256
#define C1     40257
#define K1     64
#define SP0    128
#define SP1    128
#define PS     128

typedef __attribute__((ext_vector_type(8))) short short8;
typedef __attribute__((ext_vector_type(4))) float float4v;

__device__ __forceinline__ void gld_lds16(const void* g, void* l) {
    __builtin_amdgcn_global_load_lds(
        (const __attribute__((address_space(1))) unsigned int*)g,
        (__attribute__((address_space(3))) unsigned int*)l,
        16, 0, 0);
}

__device__ __forceinline__ unsigned short f2bf(float f) {
    unsigned int u = __float_as_uint(f);
    return (unsigned short)((u + 0x7FFFu + ((u >> 16) & 1u)) >> 16);
}

__device__ __forceinline__ float bf2f(unsigned short h) {
    return __uint_as_float(((unsigned int)h) << 16);
}

// -------- all fp32->bf16 casts (x + weights) in ONE launch + init ---------
#define S0E (TOK * DIM / 4)
#define S1E (S0E + NHEAD * DIM / 4)
#define S2E (S1E + K0 * DIM / 4)
#define S3E (S2E + C0 * K0 / 4)
#define S4E (S3E + K1 * DIM / 4)
#define S5E (S4E + C1 * K1 / 4)
__global__ __launch_bounds__(256) void megacast_kernel(
    const float* __restrict__ x, const float* __restrict__ W_head,
    const float* __restrict__ W0a, const float* __restrict__ W0b,
    const float* __restrict__ W1a, const float* __restrict__ W1b,
    unsigned short* __restrict__ xh, unsigned short* __restrict__ Wheadh,
    unsigned short* __restrict__ W0ah, unsigned short* __restrict__ W0bh,
    unsigned short* __restrict__ W1ah, unsigned short* __restrict__ W1bh,
    int* __restrict__ cnt, float* __restrict__ Shead, float* __restrict__ loss)
{
    int i = blockIdx.x * 256 + threadIdx.x;
    if (i == 0) { cnt[0] = 0; cnt[1] = 0; loss[0] = 0.f; }
    if (i < TOK / 4) ((float4*)Shead)[i] = (float4){0.f, 0.f, 0.f, 0.f};
    const float* src; unsigned short* dst; int off;
    if      (i < S0E) { src = x;      dst = xh;     off = i; }
    else if (i < S1E) { src = W_head; dst = Wheadh; off = i - S0E; }
    else if (i < S2E) { src = W0a;    dst = W0ah;   off = i - S1E; }
    else if (i < S3E) { src = W0b;    dst = W0bh;   off = i - S2E; }
    else if (i < S4E) { src = W1a;    dst = W1ah;   off = i - S3E; }
    else if (i < S5E) { src = W1b;    dst = W1bh;   off = i - S4E; }
    else return;
    float4 v = ((const float4*)src)[off];
    ushort4 o;
    o.x = f2bf(v.x); o.y = f2bf(v.y); o.z = f2bf(v.z); o.w = f2bf(v.w);
    ((ushort4*)dst)[off] = o;
}

// ---- 128x64x64 bf16 MFMA GEMM (async gld_lds staging), XCD-swizzled, ----
// ---- head-softmax-fused; blocks [672,688) do target classification. -----
__global__ __launch_bounds__(256, 3) void gemm_sw(
    const unsigned short* __restrict__ Ah,
    const unsigned short* __restrict__ Wheadh, const unsigned short* __restrict__ W0ah,
    const unsigned short* __restrict__ W1ah,
    const int* __restrict__ target,
    float* __restrict__ Shead, float* __restrict__ g0, float* __restrict__ g1,
    float* __restrict__ th,
    unsigned short* __restrict__ XA0h, unsigned short* __restrict__ XA1h,
    int* __restrict__ cnt, int* __restrict__ l0, int* __restrict__ l1)
{
    const int id = blockIdx.x;
    if (id >= 672) {
        int t = (id - 672) * 256 + threadIdx.x;
        if (t < TOK) {
            int tg = target[t];
            if (tg >= NSHORT && tg < NSHORT + C0) {
                int i = atomicAdd(&cnt[0], 1); l0[i] = t;
            } else if (tg >= NSHORT + C0) {
                int i = atomicAdd(&cnt[1], 1); l1[i] = t;
            }
        }
        return;
    }
    const int xcd = id & 7, j = id >> 3;
    const int bx = j % 21, by = xcd + 8 * (j / 21);

    const unsigned short* Bh; int nrows, bn, seg, ldY; unsigned short* Yh;
    if (bx < 16)      { seg = 0; Bh = Wheadh; nrows = NHEAD; bn = bx * 64;        Yh = nullptr; ldY = 0; }
    else if (bx < 20) { seg = 1; Bh = W0ah;   nrows = K0;    bn = (bx - 16) * 64; Yh = XA0h;    ldY = K0; }
    else              { seg = 2; Bh = W1ah;   nrows = K1;    bn = 0;              Yh = XA1h;    ldY = K1; }
    const int bm = by * 128;

    __shared__ short ldsA[2][8192];
    __shared__ short ldsB[2][4096];
    const int tid = threadIdx.x, wv = tid >> 6, lane = tid & 63;
    const int nn = lane & 15, q = lane >> 4;
    const int wr = wv >> 1, wc = wv & 1;

    float4v acc[4][2];
    #pragma unroll
    for (int i = 0; i < 4; ++i)
        #pragma unroll
        for (int jj = 0; jj < 2; ++jj) acc[i][jj] = (float4v){0.f, 0.f, 0.f, 0.f};

    auto stage = [&](int b, int kk) {
        #pragma unroll
        for (int i2 = 0; i2 < 6; ++i2) {
            int ch = wv * 6 + i2;
            if (ch < 16) {
                int rg = ch >> 1, kc = ch & 1;
                int row = bm + rg * 16 + nn;
                gld_lds16(Ah + (size_t)row * DIM + kk + kc * 32 + q * 8, &ldsA[b][ch * 512]);
            } else {
                int bc = ch - 16, rg = bc >> 1, kc = bc & 1;
                int row = bn + rg * 16 + nn;
                if (row > nrows - 1) row = nrows - 1;
                gld_lds16(Bh + (size_t)row * DIM + kk + kc * 32 + q * 8, &ldsB[b][bc * 512]);
            }
        }
    };

    int buf = 0;
    stage(0, 0);
    __syncthreads();
    for (int s = 0; s < DIM / 64; ++s) {
        if (s + 1 < DIM / 64) stage(buf ^ 1, (s + 1) * 64);
        short8 afr[4][2], bfr[2][2];
        #pragma unroll
        for (int i = 0; i < 4; ++i)
            #pragma unroll
            for (int kc = 0; kc < 2; ++kc)
                afr[i][kc] = *(const short8*)&ldsA[buf][((wr * 4 + i) * 2 + kc) * 512 + lane * 8];
        #pragma unroll
        for (int jj = 0; jj < 2; ++jj)
            #pragma unroll
            for (int kc = 0; kc < 2; ++kc)
                bfr[jj][kc] = *(const short8*)&ldsB[buf][((wc * 2 + jj) * 2 + kc) * 512 + lane * 8];
        #pragma unroll
        for (int kc = 0; kc < 2; ++kc)
            #pragma unroll
            for (int i = 0; i < 4; ++i)
                #pragma unroll
                for (int jj = 0; jj < 2; ++jj)
                    acc[i][jj] = __builtin_amdgcn_mfma_f32_16x16x32_bf16(afr[i][kc], bfr[jj][kc], acc[i][jj], 0, 0, 0);
        __syncthreads();
        buf ^= 1;
    }

    if (seg == 0) {
        #pragma unroll
        for (int i = 0; i < 4; ++i) {
            int rowr[4], tg[4];
            float s[4] = {0.f, 0.f, 0.f, 0.f};
            #pragma unroll
            for (int r = 0; r < 4; ++r) {
                rowr[r] = bm + wr * 64 + i * 16 + q * 4 + r;
                tg[r] = target[rowr[r]];
            }
            #pragma unroll
            for (int jj = 0; jj < 2; ++jj) {
                int col = bn + wc * 32 + jj * 16 + nn;
                bool cv = (col < NHEAD);
                #pragma unroll
                for (int r = 0; r < 4; ++r) {
                    float v = acc[i][jj][r];
                    if (cv) {
                        s[r] += __expf(v);
                        if (col == 1000) g0[rowr[r]] = v;
                        if (col == 1001) g1[rowr[r]] = v;
                        if (tg[r] < NSHORT && col == tg[r]) th[rowr[r]] = v;
                    }
                }
            }
            #pragma unroll
            for (int off = 1; off < 16; off <<= 1)
                #pragma unroll
                for (int r = 0; r < 4; ++r) s[r] += __shfl_xor(s[r], off, 64);
            if (nn == 0) {
                #pragma unroll
                for (int r = 0; r < 4; ++r) atomicAdd(&Shead[rowr[r]], s[r]);
            }
        }
    } else {
        #pragma unroll
        for (int i = 0; i < 4; ++i)
            #pragma unroll
            for (int jj = 0; jj < 2; ++jj) {
                int col = bn + wc * 32 + jj * 16 + nn;
                if (col < nrows) {
                    #pragma unroll
                    for (int r = 0; r < 4; ++r) {
                        int row = bm + wr * 64 + i * 16 + q * 4 + r;
                        Yh[(size_t)row * ldY + col] = f2bf(acc[i][jj][r]);
                    }
                }
            }
    }
}

// ------- cluster exp-sum: LDS-staged MFMA + exp (own kernel, own LDS) -----
// Block: 128 tokens (4 waves x MT=2 m-tiles). G ctiles per buffer.
// K0: G=2 -> 32 KB dbuf (5 blocks/CU). K1: G=4 -> 16 KB dbuf (10 blocks/CU).
template<int K, int G>
__global__ __launch_bounds__(256) void cluster_lse(
    const unsigned short* __restrict__ XAh, const unsigned short* __restrict__ Wbh,
    int C, const int* __restrict__ list, const int* __restrict__ cnt, int ci,
    int tps, float* __restrict__ psum)
{
    constexpr int NCH = K / 32;
    constexpr int CPB = G * NCH;
    constexpr int MT = 2, TT = MT * 64;
    const int n = cnt[ci];
    if ((int)blockIdx.x * TT >= n) return;
    __shared__ short lds[2][CPB * 512];
    const int tid = threadIdx.x, wv = tid >> 6, lane = tid & 63;
    const int m = lane & 15, q = lane >> 4;
    const int nT = (C + 15) / 16;
    const int sp = blockIdx.y;
    const int T0 = sp * tps;
    const int T1 = min(T0 + tps, nT);
    if (T0 >= nT) return;

    short8 a[MT][NCH];
    #pragma unroll
    for (int t = 0; t < MT; ++t) {
        int iTok = blockIdx.x * TT + t * 64 + wv * 16 + m;
        int tok = list[(iTok < n) ? iTok : (n - 1)];
        const unsigned short* ap = XAh + (size_t)tok * K + q * 8;
        #pragma unroll
        for (int kc = 0; kc < NCH; ++kc) a[t][kc] = *(const short8*)(ap + kc * 32);
    }

    float s[MT][4] = {};

    auto stage = [&](int b, int Tb) {
        #pragma unroll
        for (int i = 0; i < CPB / 4; ++i) {
            int ch = wv * (CPB / 4) + i;
            int g = ch / NCH, kc = ch % NCH;
            int row = (Tb + g) * 16 + m;
            if (row > C - 1) row = C - 1;
            gld_lds16(Wbh + (size_t)row * K + kc * 32 + q * 8, &lds[b][ch * 512]);
        }
    };

    int buf = 0;
    stage(0, T0);
    __syncthreads();
    for (int Tb = T0; Tb < T1; Tb += G) {
        if (Tb + G < T1) stage(buf ^ 1, Tb + G);
        #pragma unroll
        for (int g = 0; g < G; ++g) {
            if (Tb + g < T1) {
                float4v av[MT];
                #pragma unroll
                for (int t = 0; t < MT; ++t) av[t] = (float4v){0.f, 0.f, 0.f, 0.f};
                #pragma unroll
                for (int kc = 0; kc < NCH; ++kc) {
                    short8 bfr = *(const short8*)&lds[buf][(g * NCH + kc) * 512 + lane * 8];
                    #pragma unroll
                    for (int t = 0; t < MT; ++t)
                        av[t] = __builtin_amdgcn_mfma_f32_16x16x32_bf16(a[t][kc], bfr, av[t], 0, 0, 0);
                }
                int jcl = (Tb + g) * 16 + m;
                if (jcl < C) {
                    #pragma unroll
                    for (int t = 0; t < MT; ++t)
                        #pragma unroll
                        for (int r = 0; r < 4; ++r) s[t][r] += __expf(av[t][r]);
                }
            }
        }
        __syncthreads();
        buf ^= 1;
    }
    #pragma unroll
    for (int off = 1; off < 16; off <<= 1) {
        #pragma unroll
        for (int t = 0; t < MT; ++t)
            #pragma unroll
            for (int r = 0; r < 4; ++r)
                s[t][r] += __shfl_xor(s[t][r], off, 64);
    }
    if (m == 0) {
        #pragma unroll
        for (int t = 0; t < MT; ++t)
            #pragma unroll
            for (int r = 0; r < 4; ++r) {
                int r0 = blockIdx.x * TT + t * 64 + wv * 16 + q * 4 + r;
                if (r0 < n) psum[(size_t)r0 * PS + sp] = s[t][r];
            }
    }
}

// ------- finish: shortlist out + cluster target dot/psum/gate + loss ------
__global__ __launch_bounds__(256) void finish_kernel(
    const unsigned short* __restrict__ XA0h, const unsigned short* __restrict__ W0bh,
    const unsigned short* __restrict__ XA1h, const unsigned short* __restrict__ W1bh,
    const int* __restrict__ l0, const int* __restrict__ l1,
    const int* __restrict__ cnt, const int* __restrict__ target,
    const float* __restrict__ psum0, const float* __restrict__ psum1,
    const float* __restrict__ Shead, const float* __restrict__ g0,
    const float* __restrict__ g1, const float* __restrict__ th,
    int tps0, int tps1, float* __restrict__ out, float* __restrict__ loss)
{
    const int y = blockIdx.y;
    const int tid = threadIdx.x, wv = tid >> 6, lane = tid & 63;
    float contrib = 0.f;
    if (y == 2) {
        int t = blockIdx.x * 256 + tid;
        if (t < TOK) {
            int tg = target[t];
            if (tg < NSHORT) {
                float v = th[t] - logf(Shead[t]);
                out[t] = v;
                contrib = v;
            }
        }
    } else {
        const int ci = y;
        const int n = cnt[ci];
        int i = blockIdx.x * 4 + wv;
        if (i < n) {
            const int* list = ci ? l1 : l0;
            int tok = list[i];
            float dot = 0.f, S = 0.f;
            if (ci == 0) {
                int tg = target[tok] - NSHORT;
                const unsigned short* xp = XA0h + (size_t)tok * K0;
                const unsigned short* wp = W0bh + (size_t)tg * K0;
                #pragma unroll
                for (int k = 0; k < K0 / 64; ++k)
                    dot += bf2f(xp[lane + k * 64]) * bf2f(wp[lane + k * 64]);
                int nT = (C0 + 15) / 16;
                if (lane * tps0 < nT)        S += psum0[(size_t)i * PS + lane];
                if ((lane + 64) * tps0 < nT) S += psum0[(size_t)i * PS + lane + 64];
            } else {
                int tg = target[tok] - (NSHORT + C0);
                dot = bf2f(XA1h[(size_t)tok * K1 + lane]) * bf2f(W1bh[(size_t)tg * K1 + lane]);
                int nT = (C1 + 15) / 16;
                if (lane * tps1 < nT)        S += psum1[(size_t)i * PS + lane];
                if ((lane + 64) * tps1 < nT) S += psum1[(size_t)i * PS + lane + 64];
            }
            #pragma unroll
            for (int off = 32; off; off >>= 1) {
                dot += __shfl_xor(dot, off, 64);
                S   += __shfl_xor(S, off, 64);
            }
            if (lane == 0) {
                float gate = (ci ? g1[tok] : g0[tok]) - logf(Shead[tok]);
                float v = dot - logf(S) + gate;
                out[tok] = v;
                contrib = v;
            }
        }
    }
    __shared__ float red[4];
    #pragma unroll
    for (int off = 32; off; off >>= 1) contrib += __shfl_xor(contrib, off, 64);
    if (lane == 0) red[wv] = contrib;
    __syncthreads();
    if (tid == 0) {
        float t = red[0] + red[1] + red[2] + red[3];
        if (t != 0.f) atomicAdd(loss, -t / (float)TOK);
    }
}

extern "C" void kernel_launch(void* const* d_in, const int* in_sizes, int n_in,
                              void* d_out, int out_size, void* d_ws, size_t ws_size,
                              hipStream_t stream) {
    const float* x      = (const float*)d_in[0];
    const int*   target = (const int*)  d_in[1];
    const float* W_head = (const float*)d_in[2];
    const float* W0a    = (const float*)d_in[3];
    const float* W0b    = (const float*)d_in[4];
    const float* W1a    = (const float*)d_in[5];
    const float* W1b    = (const float*)d_in[6];
    float* out  = (float*)d_out;
    float* loss = out + TOK;

    float* ws     = (float*)d_ws;
    float* Shead  = ws;                               // 4096
    float* g0     = Shead + TOK;                      // 4096
    float* g1     = g0 + TOK;                         // 4096
    float* th     = g1 + TOK;                         // 4096
    float* psum0  = th + TOK;                         // 4096*128
    float* psum1  = psum0 + (size_t)TOK * PS;         // 4096*128
    unsigned short* xh     = (unsigned short*)(psum1 + (size_t)TOK * PS);
    unsigned short* Wheadh = xh + (size_t)TOK * DIM;
    unsigned short* W0ah   = Wheadh + (size_t)NHEAD * DIM;
    unsigned short* W0bh   = W0ah + (size_t)K0 * DIM;
    unsigned short* W1ah   = W0bh + (size_t)C0 * K0;
    unsigned short* W1bh   = W1ah + (size_t)K1 * DIM;
    unsigned short* XA0h   = W1bh + (size_t)C1 * K1;
    unsigned short* XA1h   = XA0h + (size_t)TOK * K0;
    int* cnt = (int*)(XA1h + (size_t)TOK * K1);
    int* l0  = cnt + 8;
    int* l1  = l0 + TOK;

    int tps0 = ((C0 + 15) / 16 + SP0 - 1) / SP0;   // 5
    int tps1 = ((C1 + 15) / 16 + SP1 - 1) / SP1;   // 20

    megacast_kernel<<<(S5E + 255) / 256, 256, 0, stream>>>(
        x, W_head, W0a, W0b, W1a, W1b, xh, Wheadh, W0ah, W0bh, W1ah, W1bh,
        cnt, Shead, loss);

    gemm_sw<<<688, 256, 0, stream>>>(
        xh, Wheadh, W0ah, W1ah, target, Shead, g0, g1, th, XA0h, XA1h,
        cnt, l0, l1);

    cluster_lse<K0, 2><<<dim3(TOK / 128, SP0), 256, 0, stream>>>(
        XA0h, W0bh, C0, l0, cnt, 0, tps0, psum0);
    cluster_lse<K1, 4><<<dim3(TOK / 128, SP1), 256, 0, stream>>>(
        XA1h, W1bh, C1, l1, cnt, 1, tps1, psum1);

    finish_kernel<<<dim3(1024, 3), 256, 0, stream>>>(
        XA0h, W0bh, XA1h, W1bh, l0, l1, cnt, target, psum0, psum1,
        Shead, g0, g1, th, tps0, tps1, out, loss);
}